// Round 1
// baseline (492.154 us; speedup 1.0000x reference)
//
#include <hip/hip_runtime.h>
#include <hip/hip_bf16.h>

// Problem constants (fixed by the reference)
constexpr int WORDS        = 1000000;
constexpr int D            = 64;                 // EMBED_SIZE
constexpr int K            = 4;                  // BIAS_NUMBER - 1
constexpr int BATCH        = 8192;
constexpr long EMBED_ELEMS = (long)WORDS * D;    // 64,000,000
constexpr long BIAS_ELEMS  = (long)WORDS * K;    //  4,000,000
constexpr long OUT_TOTAL   = 1 + EMBED_ELEMS + BIAS_ELEMS; // 68,000,001

// ws layout (floats): [0]=acc_count, [1..4]=bias_sum[j], [5..68]=wsum[e]

__global__ void prank_compute(const float* __restrict__ in_embed,
                              const float* __restrict__ in_bias,
                              const int*   __restrict__ context_id,
                              const int*   __restrict__ target_ids,
                              const int*   __restrict__ labels,
                              float*       __restrict__ ws) {
    const int lane   = threadIdx.x & 63;
    const int wpb    = blockDim.x >> 6;
    const int wave   = blockIdx.x * wpb + (threadIdx.x >> 6);
    const int nwaves = gridDim.x * wpb;

    const int ctx = context_id[0];
    const float ce = in_embed[(size_t)ctx * D + lane];
    const float b0 = in_bias[(size_t)ctx * K + 0];
    const float b1 = in_bias[(size_t)ctx * K + 1];
    const float b2 = in_bias[(size_t)ctx * K + 2];
    const float b3 = in_bias[(size_t)ctx * K + 3];

    float cnt = 0.f, bs0 = 0.f, bs1 = 0.f, bs2 = 0.f, bs3 = 0.f, wacc = 0.f;

    for (int i = wave; i < BATCH; i += nwaves) {
        const int t   = target_ids[i];
        const int lab = labels[i];
        const float e = in_embed[(size_t)t * D + lane];
        float d = e * ce;
        #pragma unroll
        for (int off = 32; off; off >>= 1) d += __shfl_xor(d, off, 64);

        const float db0 = d - b0, db1 = d - b1, db2 = d - b2, db3 = d - b3;

        // predicted label: first j with db_j <= 0 (1-based), else K+1
        int p = K + 1;
        if (db3 <= 0.f) p = 4;
        if (db2 <= 0.f) p = 3;
        if (db1 <= 0.f) p = 2;
        if (db0 <= 0.f) p = 1;
        cnt += (p == lab) ? 1.f : 0.f;

        const float labf = (float)lab;
        // tau_j = (db_j * yt_j > 0) ? 0 : lab, yt_j = (j < lab) ? 1 : -1
        const float y0 = (0 < lab) ? 1.f : -1.f;
        const float y1 = (1 < lab) ? 1.f : -1.f;
        const float y2 = (2 < lab) ? 1.f : -1.f;
        const float y3 = (3 < lab) ? 1.f : -1.f;
        const float t0 = (db0 * y0 > 0.f) ? 0.f : labf;
        const float t1 = (db1 * y1 > 0.f) ? 0.f : labf;
        const float t2 = (db2 * y2 > 0.f) ? 0.f : labf;
        const float t3 = (db3 * y3 > 0.f) ? 0.f : labf;
        bs0 += t0; bs1 += t1; bs2 += t2; bs3 += t3;
        wacc += (t0 + t1 + t2 + t3) * e;
    }

    atomicAdd(&ws[5 + lane], wacc);
    if (lane == 0) {
        atomicAdd(&ws[0], cnt);
        atomicAdd(&ws[1], bs0);
        atomicAdd(&ws[2], bs1);
        atomicAdd(&ws[3], bs2);
        atomicAdd(&ws[4], bs3);
    }
}

// Streaming copy: out[1 .. 64e6] = in_embed, out[64e6+1 .. 68e6] = in_bias.
// Output chunks start at element 4*(c+1) -> 16B-aligned float4 stores; loads
// are 4 scalar dwords (offset by -1 elem; L1 absorbs the overlap).
__global__ void prank_copy(const float* __restrict__ in_embed,
                           const float* __restrict__ in_bias,
                           float*       __restrict__ out) {
    const long n_chunks = (OUT_TOTAL - 1 - 3) / 4;  // 16,999,999 full float4s at o>=4
    const long c = (long)blockIdx.x * blockDim.x + threadIdx.x;
    if (c >= n_chunks) return;
    const long o = 4 + 4 * c;  // output element index, 16B aligned

    float4 v;
    if (o + 3 <= EMBED_ELEMS) {
        const float* s = in_embed + (o - 1);
        v.x = s[0]; v.y = s[1]; v.z = s[2]; v.w = s[3];
    } else if (o >= EMBED_ELEMS + 1) {
        const float* s = in_bias + (o - (EMBED_ELEMS + 1));
        v.x = s[0]; v.y = s[1]; v.z = s[2]; v.w = s[3];
    } else {  // single straddling chunk at o == EMBED_ELEMS
        v.x = in_embed[EMBED_ELEMS - 1];
        v.y = in_bias[0]; v.z = in_bias[1]; v.w = in_bias[2];
    }
    *reinterpret_cast<float4*>(out + o) = v;
}

// One block of 64 threads: acc, context-row updates, and the 4 scalar tails.
__global__ void prank_fixup(const float* __restrict__ in_embed,
                            const float* __restrict__ in_bias,
                            const int*   __restrict__ context_id,
                            const float* __restrict__ ws,
                            float*       __restrict__ out) {
    const int e   = threadIdx.x;
    const int ctx = context_id[0];
    const float invB = 1.0f / (float)BATCH;

    // updated context embed row
    out[1 + (size_t)ctx * D + e] = in_embed[(size_t)ctx * D + e] + ws[5 + e] * invB;

    if (e < K) {  // updated context bias row
        out[1 + EMBED_ELEMS + (size_t)ctx * K + e] =
            in_bias[(size_t)ctx * K + e] - ws[1 + e] * invB;
    }
    if (e == 0) out[0] = ws[0] * invB;

    // scalar tails not covered by the float4 copy (patched if ctx row overlaps;
    // any overlap with the row-writes above is a benign same-value race)
    if (e >= 1 && e <= 3) {
        float v = in_embed[e - 1];
        if (ctx == 0) v += ws[5 + (e - 1)] * invB;
        out[e] = v;
    }
    if (e == 4) {
        float v = in_bias[BIAS_ELEMS - 1];
        if (ctx == WORDS - 1) v -= ws[4] * invB;
        out[OUT_TOTAL - 1] = v;
    }
}

extern "C" void kernel_launch(void* const* d_in, const int* in_sizes, int n_in,
                              void* d_out, int out_size, void* d_ws, size_t ws_size,
                              hipStream_t stream) {
    const float* in_embed   = (const float*)d_in[0];
    const float* in_bias    = (const float*)d_in[1];
    const int*   context_id = (const int*)d_in[2];
    const int*   target_ids = (const int*)d_in[3];
    const int*   labels     = (const int*)d_in[4];
    float* out = (float*)d_out;
    float* ws  = (float*)d_ws;

    hipMemsetAsync(ws, 0, (5 + D) * sizeof(float), stream);

    prank_compute<<<64, 256, 0, stream>>>(in_embed, in_bias, context_id,
                                          target_ids, labels, ws);

    const long n_chunks = (OUT_TOTAL - 1 - 3) / 4;
    const int  blocks   = (int)((n_chunks + 255) / 256);
    prank_copy<<<blocks, 256, 0, stream>>>(in_embed, in_bias, out);

    prank_fixup<<<1, 64, 0, stream>>>(in_embed, in_bias, context_id, ws, out);
}

// Round 2
// 439.966 us; speedup vs baseline: 1.1186x; 1.1186x over previous
//
#include <hip/hip_runtime.h>
#include <hip/hip_bf16.h>

// Problem constants (fixed by the reference)
constexpr int WORDS        = 1000000;
constexpr int D            = 64;                 // EMBED_SIZE
constexpr int K            = 4;                  // BIAS_NUMBER - 1
constexpr int BATCH        = 8192;
constexpr long EMBED_ELEMS = (long)WORDS * D;    // 64,000,000
constexpr long BIAS_ELEMS  = (long)WORDS * K;    //  4,000,000
constexpr long OUT_TOTAL   = 1 + EMBED_ELEMS + BIAS_ELEMS; // 68,000,001

constexpr int  CBLK     = 64;                    // compute blocks
constexpr int  SLOTS    = 69;                    // per-block partials: cnt, bs[4], wsum[64]
constexpr long N_CHUNKS = (OUT_TOTAL - 1 - 3) / 4;  // 16,999,999 float4 chunks at o>=4

// ws layout: block b in [0,64) writes SLOTS floats at ws[b*SLOTS]:
//   [0]=cnt, [1..4]=bias_sum[j], [5..68]=wsum[e]

__device__ inline float4 load4_unaligned(const float* p) {
    float4 v;
    __builtin_memcpy(&v, p, sizeof(float4));  // 4B-aligned; gfx950 widens to dwordx4
    return v;
}

// Fused kernel: blocks [0,CBLK) do the PRank math; the rest stream-copy
// in_embed|in_bias into out[1..] with 16B-aligned float4 stores.
__global__ void prank_fused(const float* __restrict__ in_embed,
                            const float* __restrict__ in_bias,
                            const int*   __restrict__ context_id,
                            const int*   __restrict__ target_ids,
                            const int*   __restrict__ labels,
                            float*       __restrict__ ws,
                            float*       __restrict__ out) {
    if (blockIdx.x < CBLK) {
        // ---------------- compute path ----------------
        __shared__ float part[4][SLOTS];
        const int lane = threadIdx.x & 63;
        const int w    = threadIdx.x >> 6;          // wave in block, 0..3
        const int wave = blockIdx.x * 4 + w;        // global wave, 0..255

        const int ctx = context_id[0];
        const float ce = in_embed[(size_t)ctx * D + lane];
        const float b0 = in_bias[(size_t)ctx * K + 0];
        const float b1 = in_bias[(size_t)ctx * K + 1];
        const float b2 = in_bias[(size_t)ctx * K + 2];
        const float b3 = in_bias[(size_t)ctx * K + 3];

        float cnt = 0.f, bs0 = 0.f, bs1 = 0.f, bs2 = 0.f, bs3 = 0.f, wacc = 0.f;

        for (int i = wave; i < BATCH; i += CBLK * 4) {
            const int t   = target_ids[i];
            const int lab = labels[i];
            const float e = in_embed[(size_t)t * D + lane];
            float d = e * ce;
            #pragma unroll
            for (int off = 32; off; off >>= 1) d += __shfl_xor(d, off, 64);

            const float db0 = d - b0, db1 = d - b1, db2 = d - b2, db3 = d - b3;

            int p = K + 1;                       // first j with db_j<=0 (1-based)
            if (db3 <= 0.f) p = 4;
            if (db2 <= 0.f) p = 3;
            if (db1 <= 0.f) p = 2;
            if (db0 <= 0.f) p = 1;
            cnt += (p == lab) ? 1.f : 0.f;

            const float labf = (float)lab;
            const float y0 = (0 < lab) ? 1.f : -1.f;
            const float y1 = (1 < lab) ? 1.f : -1.f;
            const float y2 = (2 < lab) ? 1.f : -1.f;
            const float y3 = (3 < lab) ? 1.f : -1.f;
            const float t0 = (db0 * y0 > 0.f) ? 0.f : labf;
            const float t1 = (db1 * y1 > 0.f) ? 0.f : labf;
            const float t2 = (db2 * y2 > 0.f) ? 0.f : labf;
            const float t3 = (db3 * y3 > 0.f) ? 0.f : labf;
            bs0 += t0; bs1 += t1; bs2 += t2; bs3 += t3;
            wacc += (t0 + t1 + t2 + t3) * e;
        }

        part[w][5 + lane] = wacc;
        if (lane == 0) {
            part[w][0] = cnt;
            part[w][1] = bs0; part[w][2] = bs1;
            part[w][3] = bs2; part[w][4] = bs3;
        }
        __syncthreads();
        if (threadIdx.x < SLOTS) {
            const int t = threadIdx.x;
            ws[(size_t)blockIdx.x * SLOTS + t] =
                part[0][t] + part[1][t] + part[2][t] + part[3][t];
        }
    } else {
        // ---------------- copy path ----------------
        const long c = (long)(blockIdx.x - CBLK) * blockDim.x + threadIdx.x;
        if (c >= N_CHUNKS) return;
        const long o = 4 + 4 * c;                // output element index, 16B aligned

        float4 v;
        if (o + 3 <= EMBED_ELEMS) {
            v = load4_unaligned(in_embed + (o - 1));
        } else if (o >= EMBED_ELEMS + 1) {
            v = load4_unaligned(in_bias + (o - (EMBED_ELEMS + 1)));
        } else {                                 // straddle at o == EMBED_ELEMS
            v.x = in_embed[EMBED_ELEMS - 1];
            v.y = in_bias[0]; v.z = in_bias[1]; v.w = in_bias[2];
        }
        *reinterpret_cast<float4*>(out + o) = v;
    }
}

// One 64-thread block: reduce the 64 block-partials, write acc, the updated
// context rows, and the scalar tail elements the float4 copy skipped.
__global__ void prank_fixup(const float* __restrict__ in_embed,
                            const float* __restrict__ in_bias,
                            const int*   __restrict__ context_id,
                            const float* __restrict__ ws,
                            float*       __restrict__ out) {
    __shared__ float s[SLOTS];
    const int e = threadIdx.x;                    // 0..63

    float wsum = 0.f;
    for (int b = 0; b < CBLK; ++b) wsum += ws[(size_t)b * SLOTS + 5 + e];
    s[5 + e] = wsum;
    if (e < 5) {
        float a = 0.f;
        for (int b = 0; b < CBLK; ++b) a += ws[(size_t)b * SLOTS + e];
        s[e] = a;
    }
    __syncthreads();

    const int ctx = context_id[0];
    const float invB = 1.0f / (float)BATCH;

    out[1 + (size_t)ctx * D + e] = in_embed[(size_t)ctx * D + e] + s[5 + e] * invB;

    if (e >= 1 && e <= 4) {                       // bias row, j = e-1
        out[1 + EMBED_ELEMS + (size_t)ctx * K + (e - 1)] =
            in_bias[(size_t)ctx * K + (e - 1)] - s[e] * invB;
    }
    if (e == 0) out[0] = s[0] * invB;

    // scalar tails (same-value races with the row writes above are benign)
    if (e >= 1 && e <= 3) {
        float v = in_embed[e - 1];
        if (ctx == 0) v += s[5 + (e - 1)] * invB;
        out[e] = v;
    }
    if (e == 5) {
        float v = in_bias[BIAS_ELEMS - 1];
        if (ctx == WORDS - 1) v -= s[4] * invB;
        out[OUT_TOTAL - 1] = v;
    }
}

extern "C" void kernel_launch(void* const* d_in, const int* in_sizes, int n_in,
                              void* d_out, int out_size, void* d_ws, size_t ws_size,
                              hipStream_t stream) {
    const float* in_embed   = (const float*)d_in[0];
    const float* in_bias    = (const float*)d_in[1];
    const int*   context_id = (const int*)d_in[2];
    const int*   target_ids = (const int*)d_in[3];
    const int*   labels     = (const int*)d_in[4];
    float* out = (float*)d_out;
    float* ws  = (float*)d_ws;

    const int copy_blocks = (int)((N_CHUNKS + 255) / 256);
    prank_fused<<<CBLK + copy_blocks, 256, 0, stream>>>(
        in_embed, in_bias, context_id, target_ids, labels, ws, out);

    prank_fixup<<<1, 64, 0, stream>>>(in_embed, in_bias, context_id, ws, out);
}